// Round 10
// baseline (260.276 us; speedup 1.0000x reference)
//
#include <hip/hip_runtime.h>
#include <hip/hip_bf16.h>

typedef unsigned short u16;
typedef unsigned int u32;
typedef __attribute__((ext_vector_type(8))) __bf16 bf16x8;
typedef __attribute__((ext_vector_type(4))) float f32x4;
typedef __attribute__((ext_vector_type(4))) u16 u16x4;

#define LQ 1000   // sequence length
#define MM 8000   // B*L tokens
// D=1024, H=16, HD=64, BH=128

__device__ __forceinline__ u16 f2bf(float f){
  __bf16 h = (__bf16)f;
  return __builtin_bit_cast(u16, h);
}
// async global->LDS, 16B per lane; LDS dest = wave-uniform base + lane*16 (m104/m108)
__device__ __forceinline__ void async_copy16(const void* g, void* l){
  __builtin_amdgcn_global_load_lds((const __attribute__((address_space(1))) u32*)g,
                                   (__attribute__((address_space(3))) u32*)l, 16, 0, 0);
}

// ---------------- merged preprocessing: x->bf16, Wqkv^T->bf16, Wo^T->bf16 (1 launch) ----------
__device__ __forceinline__ void ttile(const float* __restrict__ src, u16* __restrict__ dst,
                                      int R, int C, int bxt, int byt, u16 (*tile)[33]){
  const int tx = threadIdx.x & 31, ty = threadIdx.x >> 5;   // 32 x 8
  const long bx = (long)bxt * 32, by = (long)byt * 32;
  #pragma unroll
  for (int i = 0; i < 32; i += 8) tile[ty + i][tx] = f2bf(src[(by + ty + i) * C + bx + tx]);
  __syncthreads();
  #pragma unroll
  for (int i = 0; i < 32; i += 8) dst[(bx + ty + i) * R + by + tx] = tile[tx][ty + i];
}

__global__ __launch_bounds__(256)
void kprep(const float* __restrict__ x, u16* __restrict__ xb,
           const float* __restrict__ Wqkv, u16* __restrict__ WqkvT,
           const float* __restrict__ Wo, u16* __restrict__ WoT)
{
  __shared__ u16 tile[32][33];
  const int bid = blockIdx.x;
  if (bid < 2048) {
    const int t = threadIdx.x;
    for (long base = (long)bid * 1024; base < 8192000L; base += 2048L * 1024) {
      const long i = base + t * 4;
      const float4 v = *(const float4*)&x[i];
      u16x4 o; o.x = f2bf(v.x); o.y = f2bf(v.y); o.z = f2bf(v.z); o.w = f2bf(v.w);
      *(u16x4*)&xb[i] = o;
    }
  } else if (bid < 5120) {
    const int idx = bid - 2048;                    // 96 x 32 tiles, src 1024x3072
    ttile(Wqkv, WqkvT, 1024, 3072, idx % 96, idx / 96, tile);
  } else {
    const int idx = bid - 5120;                    // 32 x 32 tiles, src 1024x1024
    ttile(Wo, WoT, 1024, 1024, idx % 32, idx / 32, tile);
  }
}

// ---------------- m97-style GEMM + T2 granule swizzle (validated: ~94us, 0 conflicts) ----------
// EPI==0 (BN=128): scatter bf16 into Q [BH,L,64], K [BH,L,64], VT [BH,64,L]
template<int EPI, int BN>
__global__ __launch_bounds__(256)
void gemm128(const u16* __restrict__ A, const u16* __restrict__ BT, const float* __restrict__ bias,
             u16* __restrict__ O0, u16* __restrict__ O1, u16* __restrict__ O2,
             float* __restrict__ OF)
{
  constexpr int K = 1024;
  constexpr int NF = BN / 32;                     // B-frags per wave (wave covers BN/2 = NF*16 cols)
  __shared__ __align__(16) u16 As[2][128 * 32];
  __shared__ __align__(16) u16 Bs[2][BN * 32];
  const int t = threadIdx.x, lane = t & 63, wave = t >> 6;
  const int quad = lane >> 4, l15 = lane & 15;
  const int m0 = blockIdx.y * 128, n0 = blockIdx.x * BN;
  const int wm = (wave >> 1) * 64, wn = (wave & 1) * (BN / 2);

  f32x4 acc[4][NF] = {};

  const int srow = t >> 2;                                   // 0..63 (rows; +64 handled below)
  const int sg   = (t & 3) ^ ((srow >> 1) & 3);              // inverse T2 swizzle on source granule
  const int scol = sg * 8;
  const long aoff0 = (long)min(m0 + srow,      MM - 1) * K + scol;
  const long aoff1 = (long)min(m0 + srow + 64, MM - 1) * K + scol;
  const long boff0 = (long)(n0 + srow)      * K + scol;
  const long boff1 = (long)(n0 + srow + 64) * K + scol;
  char* AsB0 = (char*)As[0] + wave * 1024;
  char* AsB1 = (char*)As[1] + wave * 1024;
  char* BsB0 = (char*)Bs[0] + wave * 1024;
  char* BsB1 = (char*)Bs[1] + wave * 1024;

  // T2 swizzle on read side: row = (multiple of 16) + l15 -> ((row>>1)&3) == ((l15>>1)&3)
  const int swz = (l15 >> 1) & 3;

  for (int kt = 0; kt < K; kt += 64) {
    __syncthreads();
    async_copy16(A  + aoff0 + kt,      AsB0);
    async_copy16(A  + aoff1 + kt,      AsB0 + 4096);
    async_copy16(BT + boff0 + kt,      BsB0);
    if constexpr (BN == 128) async_copy16(BT + boff1 + kt,      BsB0 + 4096);
    async_copy16(A  + aoff0 + kt + 32, AsB1);
    async_copy16(A  + aoff1 + kt + 32, AsB1 + 4096);
    async_copy16(BT + boff0 + kt + 32, BsB1);
    if constexpr (BN == 128) async_copy16(BT + boff1 + kt + 32, BsB1 + 4096);
    __syncthreads();
    #pragma unroll
    for (int half = 0; half < 2; half++) {
      bf16x8 af[4], bfv[NF];
      #pragma unroll
      for (int i = 0; i < 4; i++)  af[i]  = *(const bf16x8*)&As[half][(wm + i * 16 + l15) * 32 + (quad ^ swz) * 8];
      #pragma unroll
      for (int i = 0; i < NF; i++) bfv[i] = *(const bf16x8*)&Bs[half][(wn + i * 16 + l15) * 32 + (quad ^ swz) * 8];
      #pragma unroll
      for (int mi = 0; mi < 4; mi++)
        #pragma unroll
        for (int ni = 0; ni < NF; ni++)
          acc[mi][ni] = __builtin_amdgcn_mfma_f32_16x16x32_bf16(af[mi], bfv[ni], acc[mi][ni], 0, 0, 0);
    }
  }

  float bs[NF]; int cols[NF];
  #pragma unroll
  for (int ni = 0; ni < NF; ni++) { cols[ni] = n0 + wn + ni * 16 + l15; bs[ni] = bias[cols[ni]]; }

  #pragma unroll
  for (int mi = 0; mi < 4; mi++) {
    #pragma unroll
    for (int r = 0; r < 4; r++) {
      const int row = m0 + wm + mi * 16 + quad * 4 + r;   // C/D: row = quad*4+reg, col = lane&15 (m89)
      if (row >= MM) continue;
      if (EPI == 0) {
        const int b = row / 1000, l = row - b * 1000;
        #pragma unroll
        for (int ni = 0; ni < NF; ni++) {
          const u16 o = f2bf(acc[mi][ni][r] + bs[ni]);
          const int col = cols[ni];
          const int which = col >> 10, hh = (col >> 6) & 15, dd = col & 63;
          const int bh = b * 16 + hh;
          if      (which == 0) O0[((long)bh * LQ + l) * 64 + dd] = o;
          else if (which == 1) O1[((long)bh * LQ + l) * 64 + dd] = o;
          else                 O2[((long)bh * 64 + dd) * LQ + l] = o;   // V stored transposed per head
        }
      } else {
        #pragma unroll
        for (int ni = 0; ni < NF; ni++)
          OF[(long)row * 1024 + cols[ni]] = acc[mi][ni][r] + bs[ni];    // fp32 store
      }
    }
  }
}

// ---------------- gemmO: O-projection, 128x128 tile, split-K=2 inside the block (r10) ----------
// r7 (BN=64) and r9 (64x128/2-wave) both proved: changing the tile/wave SHAPE of the small GEMM
// loses (staging:MFMA ratio degrades). gemmO keeps the validated gemm128 wave-engine BYTE-
// equivalent per group: 512 threads = 2 groups of 256; group g runs the exact gemm128 K-loop
// (same staging map, LDS layout, swizzle, 2.0 MFMA:ds ratio) over K-half [g*512,(g+1)*512) in
// its own 32KB LDS region -> 8 K-iters/block instead of 16 (per-block latency ~halves) and 2
// independent staging streams per block (16 waves/CU at 2 blocks/CU -> m114 phase diversity).
// Epilogue: group 1 dumps acc to LDS (per-fragment 4KB regions, lane-contiguous 16B -> conflict-
// free), group 0 adds + writes with bias. LDS 64KB total = 2 blocks/CU.
__global__ __launch_bounds__(512)
void gemmO(const u16* __restrict__ A, const u16* __restrict__ BT, const float* __restrict__ bias,
           float* __restrict__ OF)
{
  __shared__ __align__(16) char smem[65536];
  // staging carve: [grp*2+half] x 8KB for A (0..32KB), same for B (32..64KB)
  u16 (*As)[128 * 32] = (u16 (*)[128 * 32])smem;
  u16 (*Bs)[128 * 32] = (u16 (*)[128 * 32])(smem + 32768);
  const int grp = threadIdx.x >> 8;                 // K-half group 0/1
  const int t = threadIdx.x & 255;                  // validated 256-thread engine index
  const int lane = t & 63, wave = t >> 6;
  const int quad = lane >> 4, l15 = lane & 15;
  const int m0 = blockIdx.y * 128, n0 = blockIdx.x * 128;
  const int wm = (wave >> 1) * 64, wn = (wave & 1) * 64;
  const long kbase = grp * 512;

  f32x4 acc[4][4] = {};

  const int srow = t >> 2;                                   // 0..63
  const int sg   = (t & 3) ^ ((srow >> 1) & 3);              // inverse T2 swizzle on source granule
  const int scol = sg * 8;
  const long aoff0 = (long)min(m0 + srow,      MM - 1) * 1024 + kbase + scol;
  const long aoff1 = (long)min(m0 + srow + 64, MM - 1) * 1024 + kbase + scol;
  const long boff0 = (long)(n0 + srow)      * 1024 + kbase + scol;
  const long boff1 = (long)(n0 + srow + 64) * 1024 + kbase + scol;
  char* AsB0 = (char*)As[grp * 2 + 0] + wave * 1024;
  char* AsB1 = (char*)As[grp * 2 + 1] + wave * 1024;
  char* BsB0 = (char*)Bs[grp * 2 + 0] + wave * 1024;
  char* BsB1 = (char*)Bs[grp * 2 + 1] + wave * 1024;

  const int swz = (l15 >> 1) & 3;

  for (int kt = 0; kt < 512; kt += 64) {
    __syncthreads();
    async_copy16(A  + aoff0 + kt,      AsB0);
    async_copy16(A  + aoff1 + kt,      AsB0 + 4096);
    async_copy16(BT + boff0 + kt,      BsB0);
    async_copy16(BT + boff1 + kt,      BsB0 + 4096);
    async_copy16(A  + aoff0 + kt + 32, AsB1);
    async_copy16(A  + aoff1 + kt + 32, AsB1 + 4096);
    async_copy16(BT + boff0 + kt + 32, BsB1);
    async_copy16(BT + boff1 + kt + 32, BsB1 + 4096);
    __syncthreads();
    #pragma unroll
    for (int half = 0; half < 2; half++) {
      bf16x8 af[4], bfv[4];
      #pragma unroll
      for (int i = 0; i < 4; i++) af[i]  = *(const bf16x8*)&As[grp * 2 + half][(wm + i * 16 + l15) * 32 + (quad ^ swz) * 8];
      #pragma unroll
      for (int i = 0; i < 4; i++) bfv[i] = *(const bf16x8*)&Bs[grp * 2 + half][(wn + i * 16 + l15) * 32 + (quad ^ swz) * 8];
      #pragma unroll
      for (int mi = 0; mi < 4; mi++)
        #pragma unroll
        for (int ni = 0; ni < 4; ni++)
          acc[mi][ni] = __builtin_amdgcn_mfma_f32_16x16x32_bf16(af[mi], bfv[ni], acc[mi][ni], 0, 0, 0);
    }
  }

  // ---- cross-group K-reduction: grp1 dumps acc (64KB overlay), grp0 adds ----
  __syncthreads();                                  // all staging reads complete block-wide
  float* dump = (float*)smem;
  if (grp == 1) {
    #pragma unroll
    for (int mi = 0; mi < 4; mi++)
      #pragma unroll
      for (int ni = 0; ni < 4; ni++)
        *(f32x4*)&dump[(mi * 4 + ni) * 1024 + t * 4] = acc[mi][ni];   // 4KB region/frag, 16B/lane
  }
  __syncthreads();
  if (grp == 0) {
    #pragma unroll
    for (int mi = 0; mi < 4; mi++)
      #pragma unroll
      for (int ni = 0; ni < 4; ni++) {
        const f32x4 p = *(const f32x4*)&dump[(mi * 4 + ni) * 1024 + t * 4];
        acc[mi][ni] += p;
      }

    float bs[4]; int cols[4];
    #pragma unroll
    for (int ni = 0; ni < 4; ni++) { cols[ni] = n0 + wn + ni * 16 + l15; bs[ni] = bias[cols[ni]]; }
    #pragma unroll
    for (int mi = 0; mi < 4; mi++) {
      #pragma unroll
      for (int r = 0; r < 4; r++) {
        const int row = m0 + wm + mi * 16 + quad * 4 + r;   // C/D: row = quad*4+reg, col = lane&15
        if (row >= MM) continue;
        #pragma unroll
        for (int ni = 0; ni < 4; ni++)
          OF[(long)row * 1024 + cols[ni]] = acc[mi][ni][r] + bs[ni];  // fp32 store
      }
    }
  }
}

// ---------------- flash attention v8: pair-interleaved chunks (round-8 validated, best-known) ---
__global__ __launch_bounds__(256)
void attn_kernel(const u16* __restrict__ Qb, const u16* __restrict__ Kb,
                 const u16* __restrict__ VTb, u16* __restrict__ AO)
{
  __shared__ __align__(16) u16 Ps[4][2][16 * 40];   // [wave][qblock][q=16][key=32 +8 pad]
  const int t = threadIdx.x, lane = t & 63, wave = t >> 6;
  const int quad = lane >> 4, l15 = lane & 15;
  const int lin = blockIdx.y * 4 + blockIdx.x;      // hardware linear id (x-fastest), 0..511
  const int swz = (lin & 7) * 64 + (lin >> 3);      // XCD-chunked remap (bijective, 512%8==0)
  const int bh  = swz >> 2;                         // 0..127 (XCD r -> bh [16r,16r+16))
  const int s   = swz & 3;
  const int c   = ((wave & 2) ? 8 : 0) + ((wave & 1) ? (7 - s) : s);  // balanced c-set per block
  const int ch[2] = { c, 31 - c };                  // this wave's chunk pair
  const int nkt = 32 - c;                           // loop length = chunk ch[1]'s tile count
  const u16* Q  = Qb  + (long)bh * LQ * 64;
  const u16* Kp = Kb  + (long)bh * LQ * 64;
  const u16* VT = VTb + (long)bh * 64 * LQ;
  const int b = bh >> 4, h = bh & 15;
  const float sscale = 0.18033688011112042f;        // (1/sqrt(64)) * log2(e)

  // Q B-frags for both chunks x two 16-col q-blocks: B[k=d=quad*8+j][n=q=l15]
  int qv[2][2]; bf16x8 bq0[2][2], bq1[2][2];
  #pragma unroll
  for (int cj = 0; cj < 2; cj++) {
    #pragma unroll
    for (int g = 0; g < 2; g++) {
      qv[cj][g] = ch[cj] * 32 + g * 16 + l15;
      const int qc = min(qv[cj][g], LQ - 1);
      bq0[cj][g] = *(const bf16x8*)&Q[(long)qc * 64 +      quad * 8];
      bq1[cj][g] = *(const bf16x8*)&Q[(long)qc * 64 + 32 + quad * 8];
    }
  }

  float l_p[2][2] = {{0.f, 0.f}, {0.f, 0.f}};
  f32x4 o[2][2][4] = {};

  // prefetch tile 0 (shared K/V stream serves both chunks)
  bf16x8 pa00, pa01, pa10, pa11, pav0, pav1, pav2, pav3;
  {
    const int krA = min(l15, LQ - 1), krB = min(16 + l15, LQ - 1);
    pa00 = *(const bf16x8*)&Kp[(long)krA * 64 +      quad * 8];
    pa01 = *(const bf16x8*)&Kp[(long)krA * 64 + 32 + quad * 8];
    pa10 = *(const bf16x8*)&Kp[(long)krB * 64 +      quad * 8];
    pa11 = *(const bf16x8*)&Kp[(long)krB * 64 + 32 + quad * 8];
    const int vcol = min(quad * 8, LQ - 8);
    pav0 = *(const bf16x8*)&VT[(long)( 0 + l15) * LQ + vcol];
    pav1 = *(const bf16x8*)&VT[(long)(16 + l15) * LQ + vcol];
    pav2 = *(const bf16x8*)&VT[(long)(32 + l15) * LQ + vcol];
    pav3 = *(const bf16x8*)&VT[(long)(48 + l15) * LQ + vcol];
  }

  for (int kk = 0; kk < nkt; ++kk) {
    const int k0 = kk * 32;
    const bf16x8 a00 = pa00, a01 = pa01, a10 = pa10, a11 = pa11;
    bf16x8 av[4] = { pav0, pav1, pav2, pav3 };
    if (kk + 1 < nkt) {                             // issue next tile's loads early (wave-uniform)
      const int n0k = k0 + 32;
      const int krA = min(n0k + l15, LQ - 1), krB = min(n0k + 16 + l15, LQ - 1);
      pa00 = *(const bf16x8*)&Kp[(long)krA * 64 +      quad * 8];
      pa01 = *(const bf16x8*)&Kp[(long)krA * 64 + 32 + quad * 8];
      pa10 = *(const bf16x8*)&Kp[(long)krB * 64 +      quad * 8];
      pa11 = *(const bf16x8*)&Kp[(long)krB * 64 + 32 + quad * 8];
      const int vcol = min(n0k + quad * 8, LQ - 8);
      pav0 = *(const bf16x8*)&VT[(long)( 0 + l15) * LQ + vcol];
      pav1 = *(const bf16x8*)&VT[(long)(16 + l15) * LQ + vcol];
      pav2 = *(const bf16x8*)&VT[(long)(32 + l15) * LQ + vcol];
      pav3 = *(const bf16x8*)&VT[(long)(48 + l15) * LQ + vcol];
    }

    #pragma unroll
    for (int cj = 0; cj < 2; cj++) {
      if (cj == 0 && kk > ch[0]) continue;          // chunk c active only for kk <= c (wave-uniform)
      const bool lastt = (kk == ch[cj]);            // masked (diagonal) tile of this chunk
      #pragma unroll
      for (int g = 0; g < 2; g++) {
        const f32x4 z = {};
        __builtin_amdgcn_s_setprio(1);              // T5 (m191: attn regime)
        f32x4 s0 = __builtin_amdgcn_mfma_f32_16x16x32_bf16(a00, bq0[cj][g], z, 0, 0, 0);
        s0       = __builtin_amdgcn_mfma_f32_16x16x32_bf16(a01, bq1[cj][g], s0, 0, 0, 0);
        f32x4 s1 = __builtin_amdgcn_mfma_f32_16x16x32_bf16(a10, bq0[cj][g], z, 0, 0, 0);
        s1       = __builtin_amdgcn_mfma_f32_16x16x32_bf16(a11, bq1[cj][g], s1, 0, 0, 0);
        __builtin_amdgcn_s_setprio(0);

        float p0[4], p1[4];
        if (lastt) {                                // only the diagonal tile needs the causal mask
          const int q = qv[cj][g];
          #pragma unroll
          for (int r = 0; r < 4; r++) {
            const int key0 = k0 + quad * 4 + r;     // S^T row = key (m89)
            p0[r] = __builtin_amdgcn_exp2f((key0      <= q) ? s0[r] * sscale : -3.0e38f);
            p1[r] = __builtin_amdgcn_exp2f((key0 + 16 <= q) ? s1[r] * sscale : -3.0e38f);
          }
        } else {
          #pragma unroll
          for (int r = 0; r < 4; r++) {
            p0[r] = __builtin_amdgcn_exp2f(s0[r] * sscale);
            p1[r] = __builtin_amdgcn_exp2f(s1[r] * sscale);
          }
        }
        u16x4 w0, w1; float ls = 0.f;
        #pragma unroll
        for (int r = 0; r < 4; r++) {
          w0[r] = f2bf(p0[r]); w1[r] = f2bf(p1[r]);
          ls += p0[r] + p1[r];
        }
        l_p[cj][g] += ls;
        // P[q][key] -> per-wave LDS (same-wave sequential write->read across cj/g, proven safe)
        *(u16x4*)&Ps[wave][g][l15 * 40 + quad * 4]      = w0;
        *(u16x4*)&Ps[wave][g][l15 * 40 + 16 + quad * 4] = w1;
        // B-frag of P^T: B[k=key=quad*8+j][n=q=l15]
        const bf16x8 bp = *(const bf16x8*)&Ps[wave][g][l15 * 40 + quad * 8];
        __builtin_amdgcn_s_setprio(1);
        #pragma unroll
        for (int cc = 0; cc < 4; cc++)
          o[cj][g][cc] = __builtin_amdgcn_mfma_f32_16x16x32_bf16(av[cc], bp, o[cj][g][cc], 0, 0, 0);
        __builtin_amdgcn_s_setprio(0);
      }
    }
  }

  #pragma unroll
  for (int cj = 0; cj < 2; cj++) {
    #pragma unroll
    for (int g = 0; g < 2; g++) {
      if (qv[cj][g] >= LQ) continue;
      float l = l_p[cj][g];                         // cross-quad reduce once per chunk
      l += __shfl_xor(l, 16);
      l += __shfl_xor(l, 32);
      const float inv = 1.0f / l;
      const long base = ((long)(b * LQ + qv[cj][g])) * 1024 + h * 64;
      #pragma unroll
      for (int cc = 0; cc < 4; cc++) {              // O^T: row d = cc*16+quad*4+r, col q
        u16x4 w;
        #pragma unroll
        for (int r = 0; r < 4; r++) w[r] = f2bf(o[cj][g][cc][r] * inv);
        *(u16x4*)&AO[base + cc * 16 + quad * 4] = w; // 8B store, d-contiguous
      }
    }
  }
}

// ---------------- launcher ----------------
extern "C" void kernel_launch(void* const* d_in, const int* in_sizes, int n_in,
                              void* d_out, int out_size, void* d_ws, size_t ws_size,
                              hipStream_t stream) {
  const float* x    = (const float*)d_in[0];   // [8,1000,1024] fp32
  const float* Wqkv = (const float*)d_in[1];   // [1024,3072]  fp32
  const float* bqkv = (const float*)d_in[2];   // [3072]       fp32
  const float* Wo   = (const float*)d_in[3];   // [1024,1024]  fp32
  const float* bo   = (const float*)d_in[4];   // [1024]       fp32
  float* out = (float*)d_out;                  // [8,1000,1024] fp32

  char* ws = (char*)d_ws;                      // validated layout (rounds 2-9)
  u16* WqkvT = (u16*)(ws);                                   // 3072*1024*2 = 6291456
  u16* WoT   = (u16*)(ws + 6291456);                         // 1024*1024*2 = 2097152
  u16* xb    = (u16*)(ws + 8388608);                         // 8000*1024*2 = 16384000
  u16* Qb    = (u16*)(ws + 8388608 + 16384000L);             // 128*1000*64*2
  u16* Kb    = (u16*)(ws + 8388608 + 2 * 16384000L);
  u16* VTb   = (u16*)(ws + 8388608 + 3 * 16384000L);
  u16* AO    = xb;   // reuse: x fully consumed by gemm<0> before attn writes AO

  kprep<<<6144, 256, 0, stream>>>(x, xb, Wqkv, WqkvT, Wo, WoT);
  gemm128<0, 128><<<dim3(24, 63), 256, 0, stream>>>(xb, WqkvT, bqkv, Qb, Kb, VTb, nullptr);
  attn_kernel<<<dim3(4, 128), 256, 0, stream>>>(Qb, Kb, VTb, AO);
  gemmO<<<dim3(8, 63), 512, 0, stream>>>(AO, WoT, bo, out);
}

// Round 11
// 243.052 us; speedup vs baseline: 1.0709x; 1.0709x over previous
//
#include <hip/hip_runtime.h>
#include <hip/hip_bf16.h>

typedef unsigned short u16;
typedef unsigned int u32;
typedef __attribute__((ext_vector_type(8))) __bf16 bf16x8;
typedef __attribute__((ext_vector_type(4))) float f32x4;
typedef __attribute__((ext_vector_type(4))) u16 u16x4;

#define LQ 1000   // sequence length
#define MM 8000   // B*L tokens
// D=1024, H=16, HD=64, BH=128

__device__ __forceinline__ u16 f2bf(float f){
  __bf16 h = (__bf16)f;
  return __builtin_bit_cast(u16, h);
}
// async global->LDS, 16B per lane; LDS dest = wave-uniform base + lane*16 (m104/m108)
__device__ __forceinline__ void async_copy16(const void* g, void* l){
  __builtin_amdgcn_global_load_lds((const __attribute__((address_space(1))) u32*)g,
                                   (__attribute__((address_space(3))) u32*)l, 16, 0, 0);
}

// ---------------- merged preprocessing: x->bf16, Wqkv^T->bf16, Wo^T->bf16 (1 launch) ----------
__device__ __forceinline__ void ttile(const float* __restrict__ src, u16* __restrict__ dst,
                                      int R, int C, int bxt, int byt, u16 (*tile)[33]){
  const int tx = threadIdx.x & 31, ty = threadIdx.x >> 5;   // 32 x 8
  const long bx = (long)bxt * 32, by = (long)byt * 32;
  #pragma unroll
  for (int i = 0; i < 32; i += 8) tile[ty + i][tx] = f2bf(src[(by + ty + i) * C + bx + tx]);
  __syncthreads();
  #pragma unroll
  for (int i = 0; i < 32; i += 8) dst[(bx + ty + i) * R + by + tx] = tile[tx][ty + i];
}

__global__ __launch_bounds__(256)
void kprep(const float* __restrict__ x, u16* __restrict__ xb,
           const float* __restrict__ Wqkv, u16* __restrict__ WqkvT,
           const float* __restrict__ Wo, u16* __restrict__ WoT)
{
  __shared__ u16 tile[32][33];
  const int bid = blockIdx.x;
  if (bid < 2048) {
    const int t = threadIdx.x;
    for (long base = (long)bid * 1024; base < 8192000L; base += 2048L * 1024) {
      const long i = base + t * 4;
      const float4 v = *(const float4*)&x[i];
      u16x4 o; o.x = f2bf(v.x); o.y = f2bf(v.y); o.z = f2bf(v.z); o.w = f2bf(v.w);
      *(u16x4*)&xb[i] = o;
    }
  } else if (bid < 5120) {
    const int idx = bid - 2048;                    // 96 x 32 tiles, src 1024x3072
    ttile(Wqkv, WqkvT, 1024, 3072, idx % 96, idx / 96, tile);
  } else {
    const int idx = bid - 5120;                    // 32 x 32 tiles, src 1024x1024
    ttile(Wo, WoT, 1024, 1024, idx % 32, idx / 32, tile);
  }
}

// ---------------- m97-style GEMM + T2 granule swizzle + T1 XCD-chunked remap (r11) -------------
// r11: ONLY change vs validated round-8 kernel = bijective XCD-chunked block remap. Linear
// dispatch round-robins consecutive blocks (which share a 256KB A-row-panel) across 8 XCDs ->
// each XCD refetches the panel through its own L2 (FETCH 75.4MB vs ideal 22MB). Chunked remap
// gives each XCD a contiguous lin range: A-panel reused 24x (gemm<0>) / 8x (gemm<1>) back-to-back
// within one L2 (2MB < 4MB). Mechanism target: shorter load-return latency at the barrier's
// vmcnt drain (the 2-phase structure's known stall) — we are latency-bound, not BW-bound.
// EPI==0 (BN=128, grid 24x63): scatter bf16 into Q [BH,L,64], K [BH,L,64], VT [BH,64,L]
// EPI==1 (BN=128, grid 8x63):  OF[m*1024 + n] = fp32(acc + bias)
template<int EPI, int BN>
__global__ __launch_bounds__(256)
void gemm128(const u16* __restrict__ A, const u16* __restrict__ BT, const float* __restrict__ bias,
             u16* __restrict__ O0, u16* __restrict__ O1, u16* __restrict__ O2,
             float* __restrict__ OF)
{
  constexpr int K = 1024;
  constexpr int NF = BN / 32;                     // B-frags per wave (wave covers BN/2 = NF*16 cols)
  constexpr int NWGX = (EPI == 0) ? 24 : 8;       // grid.x (compile-time for fast div)
  constexpr int NWG  = NWGX * 63;                 // 1512 / 504, both % 8 == 0
  __shared__ __align__(16) u16 As[2][128 * 32];
  __shared__ __align__(16) u16 Bs[2][BN * 32];
  const int t = threadIdx.x, lane = t & 63, wave = t >> 6;
  const int quad = lane >> 4, l15 = lane & 15;
  int lin = blockIdx.y * NWGX + blockIdx.x;       // hardware linear id (x-fastest)
  lin = (lin & 7) * (NWG >> 3) + (lin >> 3);      // T1: XCD-chunked bijective remap
  const int m0 = (lin / NWGX) * 128, n0 = (lin % NWGX) * BN;
  const int wm = (wave >> 1) * 64, wn = (wave & 1) * (BN / 2);

  f32x4 acc[4][NF] = {};

  const int srow = t >> 2;                                   // 0..63 (rows; +64 handled below)
  const int sg   = (t & 3) ^ ((srow >> 1) & 3);              // inverse T2 swizzle on source granule
  const int scol = sg * 8;
  const long aoff0 = (long)min(m0 + srow,      MM - 1) * K + scol;
  const long aoff1 = (long)min(m0 + srow + 64, MM - 1) * K + scol;
  const long boff0 = (long)(n0 + srow)      * K + scol;
  const long boff1 = (long)(n0 + srow + 64) * K + scol;
  char* AsB0 = (char*)As[0] + wave * 1024;
  char* AsB1 = (char*)As[1] + wave * 1024;
  char* BsB0 = (char*)Bs[0] + wave * 1024;
  char* BsB1 = (char*)Bs[1] + wave * 1024;

  // T2 swizzle on read side: row = (multiple of 16) + l15 -> ((row>>1)&3) == ((l15>>1)&3)
  const int swz = (l15 >> 1) & 3;

  for (int kt = 0; kt < K; kt += 64) {
    __syncthreads();
    async_copy16(A  + aoff0 + kt,      AsB0);
    async_copy16(A  + aoff1 + kt,      AsB0 + 4096);
    async_copy16(BT + boff0 + kt,      BsB0);
    if constexpr (BN == 128) async_copy16(BT + boff1 + kt,      BsB0 + 4096);
    async_copy16(A  + aoff0 + kt + 32, AsB1);
    async_copy16(A  + aoff1 + kt + 32, AsB1 + 4096);
    async_copy16(BT + boff0 + kt + 32, BsB1);
    if constexpr (BN == 128) async_copy16(BT + boff1 + kt + 32, BsB1 + 4096);
    __syncthreads();
    #pragma unroll
    for (int half = 0; half < 2; half++) {
      bf16x8 af[4], bfv[NF];
      #pragma unroll
      for (int i = 0; i < 4; i++)  af[i]  = *(const bf16x8*)&As[half][(wm + i * 16 + l15) * 32 + (quad ^ swz) * 8];
      #pragma unroll
      for (int i = 0; i < NF; i++) bfv[i] = *(const bf16x8*)&Bs[half][(wn + i * 16 + l15) * 32 + (quad ^ swz) * 8];
      #pragma unroll
      for (int mi = 0; mi < 4; mi++)
        #pragma unroll
        for (int ni = 0; ni < NF; ni++)
          acc[mi][ni] = __builtin_amdgcn_mfma_f32_16x16x32_bf16(af[mi], bfv[ni], acc[mi][ni], 0, 0, 0);
    }
  }

  float bs[NF]; int cols[NF];
  #pragma unroll
  for (int ni = 0; ni < NF; ni++) { cols[ni] = n0 + wn + ni * 16 + l15; bs[ni] = bias[cols[ni]]; }

  #pragma unroll
  for (int mi = 0; mi < 4; mi++) {
    #pragma unroll
    for (int r = 0; r < 4; r++) {
      const int row = m0 + wm + mi * 16 + quad * 4 + r;   // C/D: row = quad*4+reg, col = lane&15 (m89)
      if (row >= MM) continue;
      if (EPI == 0) {
        const int b = row / 1000, l = row - b * 1000;
        #pragma unroll
        for (int ni = 0; ni < NF; ni++) {
          const u16 o = f2bf(acc[mi][ni][r] + bs[ni]);
          const int col = cols[ni];
          const int which = col >> 10, hh = (col >> 6) & 15, dd = col & 63;
          const int bh = b * 16 + hh;
          if      (which == 0) O0[((long)bh * LQ + l) * 64 + dd] = o;
          else if (which == 1) O1[((long)bh * LQ + l) * 64 + dd] = o;
          else                 O2[((long)bh * 64 + dd) * LQ + l] = o;   // V stored transposed per head
        }
      } else {
        #pragma unroll
        for (int ni = 0; ni < NF; ni++)
          OF[(long)row * 1024 + cols[ni]] = acc[mi][ni][r] + bs[ni];    // fp32 store
      }
    }
  }
}

// ---------------- flash attention v8: pair-interleaved chunks (round-8 validated, best-known) ---
__global__ __launch_bounds__(256)
void attn_kernel(const u16* __restrict__ Qb, const u16* __restrict__ Kb,
                 const u16* __restrict__ VTb, u16* __restrict__ AO)
{
  __shared__ __align__(16) u16 Ps[4][2][16 * 40];   // [wave][qblock][q=16][key=32 +8 pad]
  const int t = threadIdx.x, lane = t & 63, wave = t >> 6;
  const int quad = lane >> 4, l15 = lane & 15;
  const int lin = blockIdx.y * 4 + blockIdx.x;      // hardware linear id (x-fastest), 0..511
  const int swz = (lin & 7) * 64 + (lin >> 3);      // XCD-chunked remap (bijective, 512%8==0)
  const int bh  = swz >> 2;                         // 0..127 (XCD r -> bh [16r,16r+16))
  const int s   = swz & 3;
  const int c   = ((wave & 2) ? 8 : 0) + ((wave & 1) ? (7 - s) : s);  // balanced c-set per block
  const int ch[2] = { c, 31 - c };                  // this wave's chunk pair
  const int nkt = 32 - c;                           // loop length = chunk ch[1]'s tile count
  const u16* Q  = Qb  + (long)bh * LQ * 64;
  const u16* Kp = Kb  + (long)bh * LQ * 64;
  const u16* VT = VTb + (long)bh * 64 * LQ;
  const int b = bh >> 4, h = bh & 15;
  const float sscale = 0.18033688011112042f;        // (1/sqrt(64)) * log2(e)

  // Q B-frags for both chunks x two 16-col q-blocks: B[k=d=quad*8+j][n=q=l15]
  int qv[2][2]; bf16x8 bq0[2][2], bq1[2][2];
  #pragma unroll
  for (int cj = 0; cj < 2; cj++) {
    #pragma unroll
    for (int g = 0; g < 2; g++) {
      qv[cj][g] = ch[cj] * 32 + g * 16 + l15;
      const int qc = min(qv[cj][g], LQ - 1);
      bq0[cj][g] = *(const bf16x8*)&Q[(long)qc * 64 +      quad * 8];
      bq1[cj][g] = *(const bf16x8*)&Q[(long)qc * 64 + 32 + quad * 8];
    }
  }

  float l_p[2][2] = {{0.f, 0.f}, {0.f, 0.f}};
  f32x4 o[2][2][4] = {};

  // prefetch tile 0 (shared K/V stream serves both chunks)
  bf16x8 pa00, pa01, pa10, pa11, pav0, pav1, pav2, pav3;
  {
    const int krA = min(l15, LQ - 1), krB = min(16 + l15, LQ - 1);
    pa00 = *(const bf16x8*)&Kp[(long)krA * 64 +      quad * 8];
    pa01 = *(const bf16x8*)&Kp[(long)krA * 64 + 32 + quad * 8];
    pa10 = *(const bf16x8*)&Kp[(long)krB * 64 +      quad * 8];
    pa11 = *(const bf16x8*)&Kp[(long)krB * 64 + 32 + quad * 8];
    const int vcol = min(quad * 8, LQ - 8);
    pav0 = *(const bf16x8*)&VT[(long)( 0 + l15) * LQ + vcol];
    pav1 = *(const bf16x8*)&VT[(long)(16 + l15) * LQ + vcol];
    pav2 = *(const bf16x8*)&VT[(long)(32 + l15) * LQ + vcol];
    pav3 = *(const bf16x8*)&VT[(long)(48 + l15) * LQ + vcol];
  }

  for (int kk = 0; kk < nkt; ++kk) {
    const int k0 = kk * 32;
    const bf16x8 a00 = pa00, a01 = pa01, a10 = pa10, a11 = pa11;
    bf16x8 av[4] = { pav0, pav1, pav2, pav3 };
    if (kk + 1 < nkt) {                             // issue next tile's loads early (wave-uniform)
      const int n0k = k0 + 32;
      const int krA = min(n0k + l15, LQ - 1), krB = min(n0k + 16 + l15, LQ - 1);
      pa00 = *(const bf16x8*)&Kp[(long)krA * 64 +      quad * 8];
      pa01 = *(const bf16x8*)&Kp[(long)krA * 64 + 32 + quad * 8];
      pa10 = *(const bf16x8*)&Kp[(long)krB * 64 +      quad * 8];
      pa11 = *(const bf16x8*)&Kp[(long)krB * 64 + 32 + quad * 8];
      const int vcol = min(n0k + quad * 8, LQ - 8);
      pav0 = *(const bf16x8*)&VT[(long)( 0 + l15) * LQ + vcol];
      pav1 = *(const bf16x8*)&VT[(long)(16 + l15) * LQ + vcol];
      pav2 = *(const bf16x8*)&VT[(long)(32 + l15) * LQ + vcol];
      pav3 = *(const bf16x8*)&VT[(long)(48 + l15) * LQ + vcol];
    }

    #pragma unroll
    for (int cj = 0; cj < 2; cj++) {
      if (cj == 0 && kk > ch[0]) continue;          // chunk c active only for kk <= c (wave-uniform)
      const bool lastt = (kk == ch[cj]);            // masked (diagonal) tile of this chunk
      #pragma unroll
      for (int g = 0; g < 2; g++) {
        const f32x4 z = {};
        __builtin_amdgcn_s_setprio(1);              // T5 (m191: attn regime)
        f32x4 s0 = __builtin_amdgcn_mfma_f32_16x16x32_bf16(a00, bq0[cj][g], z, 0, 0, 0);
        s0       = __builtin_amdgcn_mfma_f32_16x16x32_bf16(a01, bq1[cj][g], s0, 0, 0, 0);
        f32x4 s1 = __builtin_amdgcn_mfma_f32_16x16x32_bf16(a10, bq0[cj][g], z, 0, 0, 0);
        s1       = __builtin_amdgcn_mfma_f32_16x16x32_bf16(a11, bq1[cj][g], s1, 0, 0, 0);
        __builtin_amdgcn_s_setprio(0);

        float p0[4], p1[4];
        if (lastt) {                                // only the diagonal tile needs the causal mask
          const int q = qv[cj][g];
          #pragma unroll
          for (int r = 0; r < 4; r++) {
            const int key0 = k0 + quad * 4 + r;     // S^T row = key (m89)
            p0[r] = __builtin_amdgcn_exp2f((key0      <= q) ? s0[r] * sscale : -3.0e38f);
            p1[r] = __builtin_amdgcn_exp2f((key0 + 16 <= q) ? s1[r] * sscale : -3.0e38f);
          }
        } else {
          #pragma unroll
          for (int r = 0; r < 4; r++) {
            p0[r] = __builtin_amdgcn_exp2f(s0[r] * sscale);
            p1[r] = __builtin_amdgcn_exp2f(s1[r] * sscale);
          }
        }
        u16x4 w0, w1; float ls = 0.f;
        #pragma unroll
        for (int r = 0; r < 4; r++) {
          w0[r] = f2bf(p0[r]); w1[r] = f2bf(p1[r]);
          ls += p0[r] + p1[r];
        }
        l_p[cj][g] += ls;
        // P[q][key] -> per-wave LDS (same-wave sequential write->read across cj/g, proven safe)
        *(u16x4*)&Ps[wave][g][l15 * 40 + quad * 4]      = w0;
        *(u16x4*)&Ps[wave][g][l15 * 40 + 16 + quad * 4] = w1;
        // B-frag of P^T: B[k=key=quad*8+j][n=q=l15]
        const bf16x8 bp = *(const bf16x8*)&Ps[wave][g][l15 * 40 + quad * 8];
        __builtin_amdgcn_s_setprio(1);
        #pragma unroll
        for (int cc = 0; cc < 4; cc++)
          o[cj][g][cc] = __builtin_amdgcn_mfma_f32_16x16x32_bf16(av[cc], bp, o[cj][g][cc], 0, 0, 0);
        __builtin_amdgcn_s_setprio(0);
      }
    }
  }

  #pragma unroll
  for (int cj = 0; cj < 2; cj++) {
    #pragma unroll
    for (int g = 0; g < 2; g++) {
      if (qv[cj][g] >= LQ) continue;
      float l = l_p[cj][g];                         // cross-quad reduce once per chunk
      l += __shfl_xor(l, 16);
      l += __shfl_xor(l, 32);
      const float inv = 1.0f / l;
      const long base = ((long)(b * LQ + qv[cj][g])) * 1024 + h * 64;
      #pragma unroll
      for (int cc = 0; cc < 4; cc++) {              // O^T: row d = cc*16+quad*4+r, col q
        u16x4 w;
        #pragma unroll
        for (int r = 0; r < 4; r++) w[r] = f2bf(o[cj][g][cc][r] * inv);
        *(u16x4*)&AO[base + cc * 16 + quad * 4] = w; // 8B store, d-contiguous
      }
    }
  }
}

// ---------------- launcher ----------------
extern "C" void kernel_launch(void* const* d_in, const int* in_sizes, int n_in,
                              void* d_out, int out_size, void* d_ws, size_t ws_size,
                              hipStream_t stream) {
  const float* x    = (const float*)d_in[0];   // [8,1000,1024] fp32
  const float* Wqkv = (const float*)d_in[1];   // [1024,3072]  fp32
  const float* bqkv = (const float*)d_in[2];   // [3072]       fp32
  const float* Wo   = (const float*)d_in[3];   // [1024,1024]  fp32
  const float* bo   = (const float*)d_in[4];   // [1024]       fp32
  float* out = (float*)d_out;                  // [8,1000,1024] fp32

  char* ws = (char*)d_ws;                      // validated layout (rounds 2-9)
  u16* WqkvT = (u16*)(ws);                                   // 3072*1024*2 = 6291456
  u16* WoT   = (u16*)(ws + 6291456);                         // 1024*1024*2 = 2097152
  u16* xb    = (u16*)(ws + 8388608);                         // 8000*1024*2 = 16384000
  u16* Qb    = (u16*)(ws + 8388608 + 16384000L);             // 128*1000*64*2
  u16* Kb    = (u16*)(ws + 8388608 + 2 * 16384000L);
  u16* VTb   = (u16*)(ws + 8388608 + 3 * 16384000L);
  u16* AO    = xb;   // reuse: x fully consumed by gemm<0> before attn writes AO

  kprep<<<6144, 256, 0, stream>>>(x, xb, Wqkv, WqkvT, Wo, WoT);
  gemm128<0, 128><<<dim3(24, 63), 256, 0, stream>>>(xb, WqkvT, bqkv, Qb, Kb, VTb, nullptr);
  attn_kernel<<<dim3(4, 128), 256, 0, stream>>>(Qb, Kb, VTb, AO);
  gemm128<1, 128><<<dim3(8, 63), 256, 0, stream>>>(AO, WoT, bo, nullptr, nullptr, nullptr, out);
}